// Round 5
// baseline (1474.001 us; speedup 1.0000x reference)
//
#include <hip/hip_runtime.h>

#define NEG 0.01f

typedef float f32x4 __attribute__((ext_vector_type(4)));
typedef short short8 __attribute__((ext_vector_type(8)));

__device__ __forceinline__ float lrelu(float v) { return v > 0.f ? v : NEG * v; }

// ---- bf16 hi/lo split helpers (bit tricks, RNE) ----
__device__ __forceinline__ unsigned short bf16_rne(float x) {
  unsigned u = __float_as_uint(x);
  unsigned r = u + 0x7fffu + ((u >> 16) & 1u);
  return (unsigned short)(r >> 16);
}
__device__ __forceinline__ float bf16_to_f(unsigned short h) {
  return __uint_as_float(((unsigned)h) << 16);
}

#define MFMA16(a, b, c) __builtin_amdgcn_mfma_f32_16x16x32_bf16(a, b, c, 0, 0, 0)

// =====================================================================
// Prep kernel: transposed bf16 hi/lo weight planes, BLOCKED for coalesced
// MFMA B-fragment loads: plane-local offset for (out-col n, k-elem k) =
//   ((n>>4)*(K/8) + (k>>3))*128 + (n&15)*8 + (k&7)
// so one wave's 16-lane x 16B fragment read is 256 contiguous bytes.
// ws layout (shorts):
//  0: w1hi[16384]  16384: w1lo | 32768: w2hi[65536] 98304: w2lo
//  163840: w3hi 229376: w3lo | 294912: r1hi[32768] 327680: r1lo
//  360448: r2hi 393216: r2lo | 425984: r3hi 458752: r3lo
// =====================================================================
__global__ void prep_planes(const float* __restrict__ W1, const float* __restrict__ W2,
                            const float* __restrict__ W3, const float* __restrict__ R1,
                            const float* __restrict__ R2, const float* __restrict__ R3,
                            unsigned short* __restrict__ ws) {
  int idx = blockIdx.x * 256 + threadIdx.x;
  if (idx >= 245760) return;
  const float* src; int K, N; unsigned short *hi, *lo; int e;
  if (idx < 16384)       { src = W1; K = 64;  N = 256; hi = ws;          lo = ws + 16384;  e = idx; }
  else if (idx < 81920)  { src = W2; K = 256; N = 256; hi = ws + 32768;  lo = ws + 98304;  e = idx - 16384; }
  else if (idx < 147456) { src = W3; K = 256; N = 256; hi = ws + 163840; lo = ws + 229376; e = idx - 81920; }
  else if (idx < 180224) { src = R1; K = 256; N = 128; hi = ws + 294912; lo = ws + 327680; e = idx - 147456; }
  else if (idx < 212992) { src = R2; K = 256; N = 128; hi = ws + 360448; lo = ws + 393216; e = idx - 180224; }
  else                   { src = R3; K = 256; N = 128; hi = ws + 425984; lo = ws + 458752; e = idx - 212992; }
  int n = e / K, k = e - n * K;
  int dst = ((n >> 4) * (K >> 3) + (k >> 3)) * 128 + (n & 15) * 8 + (k & 7);
  float v = src[k * N + n];
  unsigned short hb = bf16_rne(v);
  hi[dst] = hb;
  lo[dst] = bf16_rne(v - bf16_to_f(hb));
}

// =====================================================================
// Conv GEMM via MFMA: C[50(->64),256] = A[50,KK] @ W[KK,256], 3-term bf16 split.
// 8 waves; wave w covers cols [w*32, w*32+32) (2 N-tiles), all 4 M-tiles.
// A planes in LDS, [row][K] bf16, row stride 512 B, XOR-swizzle byte^=((row&7)<<4).
// B planes blocked (see prep): fragment load = contiguous 256 B per 16 lanes.
// =====================================================================
template <int KK>
__device__ __forceinline__ void conv_mfma(const char* AhiB, const char* AloB,
                                          const unsigned short* __restrict__ Whi,
                                          const unsigned short* __restrict__ Wlo,
                                          f32x4 acc[4][2], int w, int l) {
  const int g = l >> 4, r15 = l & 15;
  const int aswz = (l & 7) << 4;
  const int arow = r15 << 9;
#pragma unroll
  for (int kt = 0; kt < KK / 32; ++kt) {
    const int ka = (kt * 64 + g * 16) ^ aswz;
    short8 ah[4], al[4];
#pragma unroll
    for (int mt = 0; mt < 4; ++mt) {
      ah[mt] = *(const short8*)(AhiB + (mt * 8192 + arow + ka));
      al[mt] = *(const short8*)(AloB + (mt * 8192 + arow + ka));
    }
#pragma unroll
    for (int nt = 0; nt < 2; ++nt) {
      // blocked B: block = w*2+nt; k-subblocks 4*kt..4*kt+3 hold k = 32*kt..32*kt+31;
      // this fragment (g,r15) needs k = 32*kt + g*8 .. +8 -> subblock 4*kt (+g offset
      // folded: elements are contiguous 8-wide, lane r15 offset r15*8, g picks 16B half
      // of the 2 subblocks pair) -- load = one contiguous 16B per lane.
      const size_t bo = ((size_t)(w * 2 + nt) * (KK >> 3) + kt * 4 + g) * 128 + r15 * 8;
      short8 bh = *(const short8*)(Whi + bo);
      short8 bl = *(const short8*)(Wlo + bo);
#pragma unroll
      for (int mt = 0; mt < 4; ++mt) {
        acc[mt][nt] = MFMA16(ah[mt], bh, acc[mt][nt]);
        acc[mt][nt] = MFMA16(al[mt], bh, acc[mt][nt]);
        acc[mt][nt] = MFMA16(ah[mt], bl, acc[mt][nt]);
      }
    }
  }
}

// MLP1 via MFMA + fused relu + column-sum over nodes (mean commutes with MLP2).
__device__ __forceinline__ void mlp1_mfma(const char* AhiB, const char* AloB,
                                          const unsigned short* __restrict__ Whi,
                                          const unsigned short* __restrict__ Wlo,
                                          const float* __restrict__ b1, float* s1sum,
                                          int w, int l) {
  const int g = l >> 4, r15 = l & 15;
  const int aswz = (l & 7) << 4;
  const int arow = r15 << 9;
  const int col = w * 16 + r15;
  f32x4 acc[4] = {};
#pragma unroll
  for (int kt = 0; kt < 8; ++kt) {
    const int ka = (kt * 64 + g * 16) ^ aswz;
    // blocked B: block = w (cols w*16..w*16+16), K=256 -> 32 k-subblocks
    const size_t bo = ((size_t)w * 32 + kt * 4 + g) * 128 + r15 * 8;
    short8 bh = *(const short8*)(Whi + bo);
    short8 bl = *(const short8*)(Wlo + bo);
#pragma unroll
    for (int mt = 0; mt < 4; ++mt) {
      short8 ah = *(const short8*)(AhiB + (mt * 8192 + arow + ka));
      short8 al = *(const short8*)(AloB + (mt * 8192 + arow + ka));
      acc[mt] = MFMA16(ah, bh, acc[mt]);
      acc[mt] = MFMA16(al, bh, acc[mt]);
      acc[mt] = MFMA16(ah, bl, acc[mt]);
    }
  }
  const float b1v = b1[col];
  float colsum = 0.f;
#pragma unroll
  for (int mt = 0; mt < 4; ++mt)
#pragma unroll
    for (int r = 0; r < 4; ++r) {
      float v = fmaxf(acc[mt][r] + b1v, 0.f);
      if (mt < 3) colsum += v;                  // rows < 48 always valid
      else if (g == 0 && r < 2) colsum += v;    // rows 48,49
    }
  colsum += __shfl_xor(colsum, 16);
  colsum += __shfl_xor(colsum, 32);
  if (l < 16) s1sum[w * 16 + l] = colsum;
}

struct GnnArgs {
  const float* x;  const float* w;  const int* src;  const int* dst;
  const float* ar[4];
  const float* gamma[3]; const float* beta[3]; const float* alpha[3];
  const float* rb1[3]; const float* rW2[3]; const float* rb2[3];
  const unsigned short* whi[3]; const unsigned short* wlo[3];
  const unsigned short* rhi[3]; const unsigned short* rlo[3];
};

// Per-layer: conv(MFMA) -> 4x{stage|gather+stats|apply} -> MLP1(MFMA) -> outputs
template <int KK>
__device__ __forceinline__ void do_layer(
    char* AhiB, char* AloB, float* Cchunk, float* agg,
    const unsigned short* csr_s, const int* rs,
    const float* w_lds, float* war, const float* outs_, const float* ins_,
    float* statsS1, float* statsS2, float* wmacc, float* s1sum,
    const unsigned short* Whi, const unsigned short* Wlo,
    const unsigned short* Rhi, const unsigned short* Rlo,
    const float* gamma, const float* beta, const float* alpha,
    const float* ar_next, const float* b1, const float* rW2f, const float* b2,
    float* out, int b, int ro_off, int t, int w, int l) {
  f32x4 acc[4][2] = {};
  conv_mfma<KK>(AhiB, AloB, Whi, Wlo, acc, w, l);

  const int g = l >> 4, r15 = l & 15;
#pragma unroll 1
  for (int ch = 0; ch < 4; ++ch) {
    __syncthreads();  // B0: prev apply (stats reads) + prev gather (Cchunk) done
    if (t < 64) statsS1[t] = 0.f;
    else if (t < 128) statsS2[t - 64] = 0.f;
    if (ch == 0) {
      if (t < 256) wmacc[t] = 0.f;
      if (t < 50) war[t] = w_lds[t] * ar_next[t];
    }
    if ((w >> 1) == ch) {  // stage this chunk's C cols, outdeg-scaled, granule-swizzled
      const int cb = (w & 1) * 32;
#pragma unroll
      for (int mt = 0; mt < 4; ++mt)
#pragma unroll
        for (int nt = 0; nt < 2; ++nt)
#pragma unroll
          for (int r = 0; r < 4; ++r) {
            int row = mt * 16 + g * 4 + r;
            if (row < 50) {
              int c = cb + nt * 16 + r15;  // 0..63 within chunk
              int cp = ((((c >> 2) ^ (row & 7)) << 2) | (c & 3));
              Cchunk[row * 64 + cp] = acc[mt][nt][r] * outs_[row];
            }
          }
    }
    __syncthreads();  // B1: stage + stat-zero visible
    {  // CSR gather (float4, swizzled) + fused stats; wave w owns nodes w, w+8, ...
      const int lo4 = l & 15, hf = l >> 4;
      for (int d = w; d < 50; d += 8) {
        f32x4 v = {0.f, 0.f, 0.f, 0.f};
        const int e1 = rs[d + 1];
        for (int e = rs[d] + hf; e < e1; e += 4) {
          int s = csr_s[e];
          const f32x4 cv = *(const f32x4*)&Cchunk[s * 64 + ((lo4 ^ (s & 7)) << 2)];
          v += cv;
        }
#pragma unroll
        for (int j = 0; j < 4; ++j) {
          v[j] += __shfl_xor(v[j], 16);
          v[j] += __shfl_xor(v[j], 32);
        }
        if (hf == 0) {
          const float is = ins_[d];
          f32x4 sv = v * is;  // indeg^-0.5 folded in here once
          *(f32x4*)&agg[d * 64 + lo4 * 4] = sv;
#pragma unroll
          for (int j = 0; j < 4; ++j) {
            atomicAdd(&statsS1[lo4 * 4 + j], sv[j]);
            atomicAdd(&statsS2[lo4 * 4 + j], sv[j] * sv[j]);
          }
        }
      }
    }
    __syncthreads();  // B2: agg + stats complete
    {  // GraphNorm + lrelu + bf16 hi/lo plane write + weighted-mean partials
      const int c = t & 63, colg = ch * 64 + c;
      const float m = statsS1[c] * 0.02f;
      const float am = alpha[colg] * m;
      const float varr = statsS2[c] * 0.02f - am * (2.f * m - am);
      const float gi = gamma[colg] * rsqrtf(fmaxf(varr, 0.f) + 1e-5f);
      const float be = beta[colg];
      float wmp = 0.f;
      for (int j = 0; j < 7; ++j) {
        int n = (t >> 6) + 8 * j;
        if (n < 50) {
          float v = agg[n * 64 + c];  // already indeg-scaled
          float o = (v - am) * gi + be;
          o = o > 0.f ? o : NEG * o;
          wmp += war[n] * o;
          unsigned short hb = bf16_rne(o);
          float resid = o - bf16_to_f(hb);
          int bo = (n * 512 + 2 * colg) ^ ((n & 7) << 4);
          *(unsigned short*)(AhiB + bo) = hb;
          *(unsigned short*)(AloB + bo) = bf16_rne(resid);
        }
      }
      atomicAdd(&wmacc[colg], wmp);
    }
  }
  __syncthreads();  // planes (new h) complete
  mlp1_mfma(AhiB, AloB, Rhi, Rlo, b1, s1sum, w, l);
  __syncthreads();
  if (t < 64) {  // MLP2 on node-mean of s1 (mean commutes with linear layer)
    float a = 0.f;
    for (int k = 0; k < 128; ++k) a += s1sum[k] * rW2f[k * 64 + t];
    a = a * 0.02f + b2[t];
    out[b * 1024 + ro_off + t] = lrelu(a);
  }
  if (t < 256) out[b * 1024 + ro_off + 64 + t] = lrelu(wmacc[t] * 0.02f);
}

// min-waves/EU = 2: VGPR cap 256 so acc tile + conv temporaries stay in
// registers (round-3's (512,4) made the compiler pick 64 VGPR -> ~300 MB of
// scratch spill traffic = the entire runtime). Occupancy is LDS-bound at
// 2 blocks/CU (2x81920 B = full 160 KiB pool), so extra VGPRs cost nothing.
__global__ __launch_bounds__(512, 2) void gnn_fused(GnnArgs a, float* __restrict__ out) {
  __shared__ alignas(16) char bigb[76800];
  char* AhiB   = bigb;                      // 25600 B bf16 hi plane [50][256]
  char* AloB   = bigb + 25600;              // 25600 B bf16 lo plane
  float* Cchunk = (float*)(bigb + 51200);   // 12800 B [50][64] f32 (granule-swizzled)
  float* agg    = (float*)(bigb + 64000);   // 12800 B [50][64] f32
  __shared__ alignas(16) char smallb[4864];
  unsigned short* csr_s = (unsigned short*)smallb;      // 1024
  int*   rs      = (int*)(smallb + 1024);               // 256 (51 used)
  int*   cnt     = (int*)(smallb + 1280);               // 512 (out 0..63, in 64..127)
  float* w_lds   = (float*)(smallb + 1792);
  float* war     = (float*)(smallb + 2048);
  float* outs_   = (float*)(smallb + 2304);
  float* ins_    = (float*)(smallb + 2560);
  float* statsS1 = (float*)(smallb + 2816);
  float* statsS2 = (float*)(smallb + 3072);
  float* wmacc   = (float*)(smallb + 3328);             // 1024
  float* s1sum   = (float*)(smallb + 4352);             // 512
  int* fillp = (int*)statsS1;  // prologue-only alias

  const int t = threadIdx.x, b = blockIdx.x;
  const int l = t & 63, w = t >> 6;

  // ---- prologue: degrees, CSR build, x -> bf16 planes, weighted-mean part 0 ----
  if (t < 128) cnt[t] = 0;
  if (t < 64) fillp[t] = 0;
  if (t < 256) wmacc[t] = 0.f;
  if (t < 50) w_lds[t] = a.w[b * 50 + t];
  __syncthreads();
  int es = 0, ed = 0;
  if (t < 500) {
    es = a.src[b * 500 + t];
    ed = a.dst[b * 500 + t];
    atomicAdd(&cnt[es], 1);
    atomicAdd(&cnt[64 + ed], 1);
  }
  __syncthreads();
  if (t < 50) {
    outs_[t] = rsqrtf(fmaxf((float)cnt[t], 1.f));
    ins_[t]  = rsqrtf(fmaxf((float)cnt[64 + t], 1.f));
    war[t] = w_lds[t] * a.ar[0][t];
  }
  if (t == 0) {
    int run = 0;
    for (int n = 0; n < 50; ++n) { rs[n] = run; run += cnt[64 + n]; }
    rs[50] = run;
  }
  __syncthreads();
  if (t < 500) {
    int pos = rs[ed] + atomicAdd(&fillp[ed], 1);
    csr_s[pos] = (unsigned short)es;
  }
  {  // x load -> hi/lo planes (cols 0..63) + part-0 weighted mean
    const int c = t & 63;
    float wmp = 0.f;
    for (int j = 0; j < 7; ++j) {
      int n = (t >> 6) + 8 * j;
      if (n < 50) {
        float v = a.x[b * 3200 + n * 64 + c];
        wmp += war[n] * v;
        unsigned short hb = bf16_rne(v);
        float resid = v - bf16_to_f(hb);
        int bo = (n * 512 + 2 * c) ^ ((n & 7) << 4);
        *(unsigned short*)(AhiB + bo) = hb;
        *(unsigned short*)(AloB + bo) = bf16_rne(resid);
      }
    }
    atomicAdd(&wmacc[c], wmp);
  }
  __syncthreads();
  if (t < 64) out[b * 1024 + t] = lrelu(wmacc[t] * 0.02f);
  // (wmacc re-zeroed after the next barrier inside do_layer chunk 0)

  do_layer<64>(AhiB, AloB, Cchunk, agg, csr_s, rs, w_lds, war, outs_, ins_,
               statsS1, statsS2, wmacc, s1sum,
               a.whi[0], a.wlo[0], a.rhi[0], a.rlo[0],
               a.gamma[0], a.beta[0], a.alpha[0], a.ar[1],
               a.rb1[0], a.rW2[0], a.rb2[0], out, b, 64, t, w, l);
  do_layer<256>(AhiB, AloB, Cchunk, agg, csr_s, rs, w_lds, war, outs_, ins_,
                statsS1, statsS2, wmacc, s1sum,
                a.whi[1], a.wlo[1], a.rhi[1], a.rlo[1],
                a.gamma[1], a.beta[1], a.alpha[1], a.ar[2],
                a.rb1[1], a.rW2[1], a.rb2[1], out, b, 384, t, w, l);
  do_layer<256>(AhiB, AloB, Cchunk, agg, csr_s, rs, w_lds, war, outs_, ins_,
                statsS1, statsS2, wmacc, s1sum,
                a.whi[2], a.wlo[2], a.rhi[2], a.rlo[2],
                a.gamma[2], a.beta[2], a.alpha[2], a.ar[3],
                a.rb1[2], a.rW2[2], a.rb2[2], out, b, 704, t, w, l);
}

extern "C" void kernel_launch(void* const* d_in, const int* in_sizes, int n_in,
                              void* d_out, int out_size, void* d_ws, size_t ws_size,
                              hipStream_t stream) {
  const float* W1 = (const float*)d_in[4];
  const float* W2 = (const float*)d_in[5];
  const float* W3 = (const float*)d_in[6];
  const float* R1 = (const float*)d_in[14];
  const float* R2 = (const float*)d_in[21];
  const float* R3 = (const float*)d_in[28];
  unsigned short* ws = (unsigned short*)d_ws;

  hipLaunchKernelGGL(prep_planes, dim3(960), dim3(256), 0, stream,
                     W1, W2, W3, R1, R2, R3, ws);

  GnnArgs a;
  a.x = (const float*)d_in[0];
  a.w = (const float*)d_in[1];
  a.src = (const int*)d_in[2];
  a.dst = (const int*)d_in[3];
  a.ar[0] = (const float*)d_in[7];
  a.ar[1] = (const float*)d_in[8];
  a.ar[2] = (const float*)d_in[9];
  a.ar[3] = (const float*)d_in[10];
  for (int i = 0; i < 3; ++i) {
    a.gamma[i] = (const float*)d_in[11 + 7 * i];
    a.beta[i]  = (const float*)d_in[12 + 7 * i];
    a.alpha[i] = (const float*)d_in[13 + 7 * i];
    a.rb1[i]   = (const float*)d_in[15 + 7 * i];
    a.rW2[i]   = (const float*)d_in[16 + 7 * i];
    a.rb2[i]   = (const float*)d_in[17 + 7 * i];
  }
  a.whi[0] = ws;          a.wlo[0] = ws + 16384;
  a.whi[1] = ws + 32768;  a.wlo[1] = ws + 98304;
  a.whi[2] = ws + 163840; a.wlo[2] = ws + 229376;
  a.rhi[0] = ws + 294912; a.rlo[0] = ws + 327680;
  a.rhi[1] = ws + 360448; a.rlo[1] = ws + 393216;
  a.rhi[2] = ws + 425984; a.rlo[2] = ws + 458752;

  const int B = in_sizes[0] / 3200;
  hipLaunchKernelGGL(gnn_fused, dim3(B), dim3(512), 0, stream, a, (float*)d_out);
}